// Round 1
// baseline (382.405 us; speedup 1.0000x reference)
//
#include <hip/hip_runtime.h>
#include <hip/hip_bf16.h>
#include <stdint.h>

#define B_  2
#define S_  2048
#define D_  1024
#define H_  16
#define DH_ 64

typedef __attribute__((ext_vector_type(8))) __bf16 bf16x8;
typedef __attribute__((ext_vector_type(4))) float  f32x4;

__device__ inline unsigned short f2bf(float f) {
    union { float f; uint32_t u; } v; v.f = f;
    uint32_t r = (v.u + 0x7fffu + ((v.u >> 16) & 1u)) >> 16;
    return (unsigned short)r;
}

// ---------------- conversion kernels ----------------

__global__ void convert_x(const float* __restrict__ x, unsigned short* __restrict__ xb, int n) {
    int i = (blockIdx.x * blockDim.x + threadIdx.x) * 4;
    if (i < n) {
        float4 v = *(const float4*)(x + i);
        ushort4 o;
        o.x = f2bf(v.x); o.y = f2bf(v.y); o.z = f2bf(v.z); o.w = f2bf(v.w);
        *(ushort4*)(xb + i) = o;
    }
}

// transpose+convert 1024x1024 fp32 [K][N] -> bf16 [N][K]; z selects matrix
__global__ void transpose_w(const float* __restrict__ s0, const float* __restrict__ s1,
                            const float* __restrict__ s2, const float* __restrict__ s3,
                            unsigned short* __restrict__ d0, unsigned short* __restrict__ d1,
                            unsigned short* __restrict__ d2, unsigned short* __restrict__ d3) {
    __shared__ float tile[32][33];
    const float* src; unsigned short* dst;
    switch (blockIdx.z) {
        case 0: src = s0; dst = d0; break;
        case 1: src = s1; dst = d1; break;
        case 2: src = s2; dst = d2; break;
        default: src = s3; dst = d3; break;
    }
    int n0 = blockIdx.x * 32, k0 = blockIdx.y * 32;
    int tx = threadIdx.x, ty = threadIdx.y;   // (32, 8)
    for (int j = 0; j < 32; j += 8)
        tile[ty + j][tx] = src[(long)(k0 + ty + j) * 1024 + n0 + tx];
    __syncthreads();
    for (int j = 0; j < 32; j += 8)
        dst[(long)(n0 + ty + j) * 1024 + k0 + tx] = f2bf(tile[tx][ty + j]);
}

// ---------------- 128x128 MFMA GEMM ----------------
// A [M,1024] bf16 row-major; Bt [N,1024] bf16 row-major (i.e. B transposed).
// MODE 0: scatter epilogue -> Q[B,H,S,64], K[B,H,S,64], Vt[B,H,64,S] (bf16)
// MODE 1: C fp32 [M,1024] row-major
template<int MODE>
__global__ __launch_bounds__(256, 2)
void gemm128(const unsigned short* __restrict__ A, const unsigned short* __restrict__ Bt,
             unsigned short* __restrict__ Qo, unsigned short* __restrict__ Ko,
             unsigned short* __restrict__ Vt, float* __restrict__ Cout)
{
    __shared__ unsigned short As[128 * 72];
    __shared__ unsigned short Bs[128 * 72];
    const int tid  = threadIdx.x;
    const int lane = tid & 63, wid = tid >> 6;
    const int quad = lane >> 4, l15 = lane & 15;
    const int wm = wid >> 1, wn = wid & 1;
    const int bm = blockIdx.y, bn = blockIdx.x;
    const int K = 1024;
    f32x4 acc[4][4] = {};
    const long Abase = (long)bm * 128 * K;
    const long Bbase = (long)bn * 128 * K;

    for (int k0 = 0; k0 < K; k0 += 64) {
        __syncthreads();
        for (int i = 0; i < 4; i++) {
            int c = tid + 256 * i;            // 0..1023 chunk id
            int row = c >> 3, cc = c & 7;     // 8 x 16B chunks per row of 64 bf16
            uint4 va = *(const uint4*)(A + Abase + (long)row * K + k0 + cc * 8);
            *(uint4*)(As + row * 72 + cc * 8) = va;
            uint4 vb = *(const uint4*)(Bt + Bbase + (long)row * K + k0 + cc * 8);
            *(uint4*)(Bs + row * 72 + cc * 8) = vb;
        }
        __syncthreads();
        for (int ks = 0; ks < 2; ks++) {
            bf16x8 af[4], bfr[4];
            for (int t = 0; t < 4; t++) {
                af[t]  = *(const bf16x8*)(As + (wm * 64 + t * 16 + l15) * 72 + ks * 32 + quad * 8);
                bfr[t] = *(const bf16x8*)(Bs + (wn * 64 + t * 16 + l15) * 72 + ks * 32 + quad * 8);
            }
            for (int tm = 0; tm < 4; tm++)
                for (int tn = 0; tn < 4; tn++)
                    acc[tm][tn] = __builtin_amdgcn_mfma_f32_16x16x32_bf16(af[tm], bfr[tn], acc[tm][tn], 0, 0, 0);
        }
    }

    for (int tm = 0; tm < 4; tm++)
        for (int tn = 0; tn < 4; tn++)
            for (int r = 0; r < 4; r++) {
                int gm = bm * 128 + wm * 64 + tm * 16 + quad * 4 + r;  // row (C layout: quad*4+reg)
                int gn = bn * 128 + wn * 64 + tn * 16 + l15;           // col (lane&15)
                float v = acc[tm][tn][r];
                if (MODE == 0) {
                    int b = gm >> 11, s = gm & 2047;
                    unsigned short bv = f2bf(v);
                    if (gn < 1024) {
                        int h = gn >> 6, d = gn & 63;
                        Qo[(((long)(b * H_ + h) * S_ + s) << 6) + d] = bv;
                    } else if (gn < 2048) {
                        int g = gn - 1024; int h = g >> 6, d = g & 63;
                        Ko[(((long)(b * H_ + h) * S_ + s) << 6) + d] = bv;
                    } else {
                        int g = gn - 2048; int h = g >> 6, d = g & 63;
                        Vt[((long)(b * H_ + h) * DH_ + d) * S_ + s] = bv;
                    }
                } else {
                    Cout[(long)gm * 1024 + gn] = v;
                }
            }
}

// ---------------- flash attention with multiplicative fractal bias ----------------
// grid (S/64, B*H), 256 threads = 4 waves, each wave owns 16 query rows.
__global__ __launch_bounds__(256, 2)
void attn_kernel(const unsigned short* __restrict__ Q, const unsigned short* __restrict__ Kb,
                 const unsigned short* __restrict__ Vt, const float* __restrict__ fw,
                 unsigned short* __restrict__ O)
{
    __shared__ float fws[2048];
    __shared__ unsigned short P[2][4][16 * 72];   // double-buffered per-wave P strips
    const int tid  = threadIdx.x;
    const int lane = tid & 63, wid = tid >> 6;
    const int quad = lane >> 4, l15 = lane & 15;
    const int bh = blockIdx.y;
    const int qt = blockIdx.x;

    for (int i = tid; i < 2048; i += 256) fws[i] = fw[i];

    const unsigned short* Qbase = Q + ((long)bh * S_ + qt * 64 + wid * 16 + l15) * DH_;
    bf16x8 qf0 = *(const bf16x8*)(Qbase + quad * 8);
    bf16x8 qf1 = *(const bf16x8*)(Qbase + 32 + quad * 8);
    const unsigned short* Kbase = Kb + (long)bh * S_ * DH_;
    const unsigned short* Vbase = Vt + (long)bh * DH_ * S_;

    f32x4 oacc[4] = {};
    float m_r[4], l_r[4];
    for (int r = 0; r < 4; r++) { m_r[r] = -1e30f; l_r[r] = 0.f; }
    __syncthreads();   // fws ready

    const float scale = 0.125f;   // 1/sqrt(64)
    for (int kt = 0; kt < S_ / 64; kt++) {
        // ---- S tile = Q K^T : 16 q-rows x 64 keys per wave ----
        f32x4 sacc[4] = {};
        for (int t = 0; t < 4; t++) {
            const unsigned short* kp = Kbase + (long)(kt * 64 + t * 16 + l15) * DH_ + quad * 8;
            bf16x8 kf0 = *(const bf16x8*)(kp);
            bf16x8 kf1 = *(const bf16x8*)(kp + 32);
            sacc[t] = __builtin_amdgcn_mfma_f32_16x16x32_bf16(qf0, kf0, sacc[t], 0, 0, 0);
            sacc[t] = __builtin_amdgcn_mfma_f32_16x16x32_bf16(qf1, kf1, sacc[t], 0, 0, 0);
        }
        float w4[4];
        for (int t = 0; t < 4; t++) w4[t] = fws[kt * 64 + t * 16 + l15] * scale;

        float s[4][4], mx[4];
        for (int r = 0; r < 4; r++) mx[r] = -1e30f;
        for (int t = 0; t < 4; t++)
            for (int r = 0; r < 4; r++) {
                s[t][r] = sacc[t][r] * w4[t];     // multiplicative bias BEFORE softmax
                mx[r] = fmaxf(mx[r], s[t][r]);
            }
        for (int d = 1; d < 16; d <<= 1)
            for (int r = 0; r < 4; r++)
                mx[r] = fmaxf(mx[r], __shfl_xor(mx[r], d));

        float alpha[4], rs[4], p[4][4];
        for (int r = 0; r < 4; r++) {
            float mn = fmaxf(m_r[r], mx[r]);
            alpha[r] = __expf(m_r[r] - mn);
            m_r[r] = mn;
            rs[r] = 0.f;
        }
        for (int t = 0; t < 4; t++)
            for (int r = 0; r < 4; r++) {
                p[t][r] = __expf(s[t][r] - m_r[r]);
                rs[r] += p[t][r];
            }
        for (int d = 1; d < 16; d <<= 1)
            for (int r = 0; r < 4; r++)
                rs[r] += __shfl_xor(rs[r], d);
        for (int r = 0; r < 4; r++) l_r[r] = l_r[r] * alpha[r] + rs[r];
        for (int t = 0; t < 4; t++)
            for (int r = 0; r < 4; r++)
                oacc[t][r] *= alpha[r];

        // ---- P: C-layout -> LDS -> A-layout ----
        unsigned short* pb = P[kt & 1][wid];
        for (int t = 0; t < 4; t++)
            for (int r = 0; r < 4; r++)
                pb[(quad * 4 + r) * 72 + t * 16 + l15] = f2bf(p[t][r]);
        __syncthreads();

        // ---- O += P V ----
        for (int ks = 0; ks < 2; ks++) {
            bf16x8 pf = *(const bf16x8*)(pb + l15 * 72 + ks * 32 + quad * 8);
            for (int t = 0; t < 4; t++) {
                const unsigned short* vp = Vbase + (long)(t * 16 + l15) * S_ + kt * 64 + ks * 32 + quad * 8;
                bf16x8 vf = *(const bf16x8*)(vp);
                oacc[t] = __builtin_amdgcn_mfma_f32_16x16x32_bf16(pf, vf, oacc[t], 0, 0, 0);
            }
        }
    }

    // epilogue: normalize, store O as [B, S, H*DV] bf16
    int b = bh >> 4, h = bh & 15;
    for (int t = 0; t < 4; t++)
        for (int r = 0; r < 4; r++) {
            int srow = qt * 64 + wid * 16 + quad * 4 + r;
            float v = oacc[t][r] / l_r[r];
            O[((long)(b * S_ + srow)) * 1024 + h * DH_ + t * 16 + l15] = f2bf(v);
        }
}

// ---------------- launch ----------------

extern "C" void kernel_launch(void* const* d_in, const int* in_sizes, int n_in,
                              void* d_out, int out_size, void* d_ws, size_t ws_size,
                              hipStream_t stream)
{
    const float* x  = (const float*)d_in[0];
    const float* Wq = (const float*)d_in[1];
    const float* Wk = (const float*)d_in[2];
    const float* Wv = (const float*)d_in[3];
    const float* Wo = (const float*)d_in[4];
    const float* fw = (const float*)d_in[5];
    float* out = (float*)d_out;

    char* ws = (char*)d_ws;
    unsigned short* xb    = (unsigned short*)(ws);               // 8 MB   [B*S, D] bf16
    unsigned short* WqkvT = (unsigned short*)(ws + 8388608);     // 6 MB   [3072,1024] bf16 (transposed)
    unsigned short* WoT   = (unsigned short*)(ws + 14680064);    // 2 MB   [1024,1024] bf16 (transposed)
    unsigned short* Qb    = (unsigned short*)(ws + 16777216);    // 8 MB   [B,H,S,64]
    unsigned short* Kb    = (unsigned short*)(ws + 25165824);    // 8 MB   [B,H,S,64]
    unsigned short* Vt    = (unsigned short*)(ws + 33554432);    // 8 MB   [B,H,64,S]
    unsigned short* Ob    = xb;                                  // alias: xb dead after gemm1

    convert_x<<<dim3((B_ * S_ * D_) / 4 / 256), dim3(256), 0, stream>>>(x, xb, B_ * S_ * D_);
    transpose_w<<<dim3(32, 32, 4), dim3(32, 8), 0, stream>>>(
        Wq, Wk, Wv, Wo,
        WqkvT, WqkvT + 1024 * 1024, WqkvT + 2 * 1024 * 1024, WoT);
    gemm128<0><<<dim3(24, 32), dim3(256), 0, stream>>>(xb, WqkvT, Qb, Kb, Vt, (float*)nullptr);
    attn_kernel<<<dim3(S_ / 64, B_ * H_), dim3(256), 0, stream>>>(Qb, Kb, Vt, fw, Ob);
    gemm128<1><<<dim3(8, 32), dim3(256), 0, stream>>>(Ob, WoT,
        (unsigned short*)nullptr, (unsigned short*)nullptr, (unsigned short*)nullptr, out);
}

// Round 2
// 381.957 us; speedup vs baseline: 1.0012x; 1.0012x over previous
//
#include <hip/hip_runtime.h>
#include <hip/hip_bf16.h>
#include <stdint.h>

#define B_  2
#define S_  2048
#define D_  1024
#define H_  16
#define DH_ 64

typedef __attribute__((ext_vector_type(8))) __bf16 bf16x8;
typedef __attribute__((ext_vector_type(4))) float  f32x4;

__device__ inline unsigned short f2bf(float f) {
    union { float f; uint32_t u; } v; v.f = f;
    uint32_t r = (v.u + 0x7fffu + ((v.u >> 16) & 1u)) >> 16;
    return (unsigned short)r;
}

// ---------------- conversion kernels ----------------

__global__ void convert_x(const float* __restrict__ x, unsigned short* __restrict__ xb, int n) {
    int i = (blockIdx.x * blockDim.x + threadIdx.x) * 4;
    if (i < n) {
        float4 v = *(const float4*)(x + i);
        ushort4 o;
        o.x = f2bf(v.x); o.y = f2bf(v.y); o.z = f2bf(v.z); o.w = f2bf(v.w);
        *(ushort4*)(xb + i) = o;
    }
}

// transpose+convert 1024x1024 fp32 [K][N] -> bf16 [N][K]; z selects matrix
__global__ void transpose_w(const float* __restrict__ s0, const float* __restrict__ s1,
                            const float* __restrict__ s2, const float* __restrict__ s3,
                            unsigned short* __restrict__ d0, unsigned short* __restrict__ d1,
                            unsigned short* __restrict__ d2, unsigned short* __restrict__ d3) {
    __shared__ float tile[32][33];
    const float* src; unsigned short* dst;
    switch (blockIdx.z) {
        case 0: src = s0; dst = d0; break;
        case 1: src = s1; dst = d1; break;
        case 2: src = s2; dst = d2; break;
        default: src = s3; dst = d3; break;
    }
    int n0 = blockIdx.x * 32, k0 = blockIdx.y * 32;
    int tx = threadIdx.x, ty = threadIdx.y;   // (32, 8)
    for (int j = 0; j < 32; j += 8)
        tile[ty + j][tx] = src[(long)(k0 + ty + j) * 1024 + n0 + tx];
    __syncthreads();
    for (int j = 0; j < 32; j += 8)
        dst[(long)(n0 + ty + j) * 1024 + k0 + tx] = f2bf(tile[tx][ty + j]);
}

// ---------------- 128x128 MFMA GEMM ----------------
// A [M,1024] bf16 row-major; Bt [N,1024] bf16 row-major (i.e. B transposed).
// MODE 0: scatter epilogue -> Q[B,H,S,64], K[B,H,S,64], Vt[B,H,64,S] (bf16)
// MODE 1: C fp32 [M,1024] row-major
template<int MODE>
__global__ __launch_bounds__(256, 2)
void gemm128(const unsigned short* __restrict__ A, const unsigned short* __restrict__ Bt,
             unsigned short* __restrict__ Qo, unsigned short* __restrict__ Ko,
             unsigned short* __restrict__ Vt, float* __restrict__ Cout)
{
    __shared__ unsigned short As[128 * 72];
    __shared__ unsigned short Bs[128 * 72];
    const int tid  = threadIdx.x;
    const int lane = tid & 63, wid = tid >> 6;
    const int quad = lane >> 4, l15 = lane & 15;
    const int wm = wid >> 1, wn = wid & 1;
    const int bm = blockIdx.y, bn = blockIdx.x;
    const int K = 1024;
    f32x4 acc[4][4] = {};
    const long Abase = (long)bm * 128 * K;
    const long Bbase = (long)bn * 128 * K;

    for (int k0 = 0; k0 < K; k0 += 64) {
        __syncthreads();
        for (int i = 0; i < 4; i++) {
            int c = tid + 256 * i;            // 0..1023 chunk id
            int row = c >> 3, cc = c & 7;     // 8 x 16B chunks per row of 64 bf16
            uint4 va = *(const uint4*)(A + Abase + (long)row * K + k0 + cc * 8);
            *(uint4*)(As + row * 72 + cc * 8) = va;
            uint4 vb = *(const uint4*)(Bt + Bbase + (long)row * K + k0 + cc * 8);
            *(uint4*)(Bs + row * 72 + cc * 8) = vb;
        }
        __syncthreads();
        for (int ks = 0; ks < 2; ks++) {
            bf16x8 af[4], bfr[4];
            for (int t = 0; t < 4; t++) {
                af[t]  = *(const bf16x8*)(As + (wm * 64 + t * 16 + l15) * 72 + ks * 32 + quad * 8);
                bfr[t] = *(const bf16x8*)(Bs + (wn * 64 + t * 16 + l15) * 72 + ks * 32 + quad * 8);
            }
            for (int tm = 0; tm < 4; tm++)
                for (int tn = 0; tn < 4; tn++)
                    acc[tm][tn] = __builtin_amdgcn_mfma_f32_16x16x32_bf16(af[tm], bfr[tn], acc[tm][tn], 0, 0, 0);
        }
    }

    for (int tm = 0; tm < 4; tm++)
        for (int tn = 0; tn < 4; tn++)
            for (int r = 0; r < 4; r++) {
                int gm = bm * 128 + wm * 64 + tm * 16 + quad * 4 + r;  // row (C layout: quad*4+reg)
                int gn = bn * 128 + wn * 64 + tn * 16 + l15;           // col (lane&15)
                float v = acc[tm][tn][r];
                if (MODE == 0) {
                    int b = gm >> 11, s = gm & 2047;
                    unsigned short bv = f2bf(v);
                    if (gn < 1024) {
                        int h = gn >> 6, d = gn & 63;
                        Qo[(((long)(b * H_ + h) * S_ + s) << 6) + d] = bv;
                    } else if (gn < 2048) {
                        int g = gn - 1024; int h = g >> 6, d = g & 63;
                        Ko[(((long)(b * H_ + h) * S_ + s) << 6) + d] = bv;
                    } else {
                        int g = gn - 2048; int h = g >> 6, d = g & 63;
                        Vt[((long)(b * H_ + h) * DH_ + d) * S_ + s] = bv;
                    }
                } else {
                    Cout[(long)gm * 1024 + gn] = v;
                }
            }
}

// ---------------- flash-style attention, barrier-free ----------------
// grid (S/64, B*H), 256 threads = 4 waves, each wave owns 16 query rows.
// Key numerics: fractal weights sum to 1 (max ~2e-3), so biased scores are
// bounded |s| < ~0.1 -> exp(s) is safe WITHOUT max subtraction. This removes
// both per-iteration shuffle reductions and the O-accumulator rescale; the
// row-sum l is accumulated per-lane and reduced once at the end.
// P strips are per-wave-private LDS -> NO __syncthreads anywhere.
// K tile kt+1 is prefetched into registers during softmax of kt; V for kt is
// issued at the top of the iteration and consumed at the bottom.
__global__ __launch_bounds__(256, 2)
void attn_kernel(const unsigned short* __restrict__ Q, const unsigned short* __restrict__ Kb,
                 const unsigned short* __restrict__ Vt, const float* __restrict__ fw,
                 unsigned short* __restrict__ O)
{
    __shared__ unsigned short P[2][4][16 * 72];
    const int tid  = threadIdx.x;
    const int lane = tid & 63, wid = tid >> 6;
    const int quad = lane >> 4, l15 = lane & 15;
    const int bh = blockIdx.y;
    const int qt = blockIdx.x;

    const unsigned short* Qp = Q + ((long)bh * S_ + qt * 64 + wid * 16 + l15) * DH_ + quad * 8;
    bf16x8 qf0 = *(const bf16x8*)(Qp);
    bf16x8 qf1 = *(const bf16x8*)(Qp + 32);
    const unsigned short* Kbase = Kb + (long)bh * S_ * DH_ + (long)l15 * DH_ + quad * 8;
    const unsigned short* Vbase = Vt + (long)bh * DH_ * S_ + (long)l15 * S_ + quad * 8;

    f32x4 oacc[4] = {};
    float l_r[4] = {0.f, 0.f, 0.f, 0.f};

    // prefetch K tile 0
    bf16x8 kf[8];
#pragma unroll
    for (int t = 0; t < 4; t++) {
        const unsigned short* kp = Kbase + (long)(t * 16) * DH_;
        kf[2 * t]     = *(const bf16x8*)(kp);
        kf[2 * t + 1] = *(const bf16x8*)(kp + 32);
    }

    for (int kt = 0; kt < S_ / 64; kt++) {
        // V loads for this tile (consumed at the bottom) + per-key fractal weights
        bf16x8 vf[8];
#pragma unroll
        for (int t = 0; t < 4; t++) {
            const unsigned short* vp = Vbase + (long)(t * 16) * S_ + kt * 64;
            vf[2 * t]     = *(const bf16x8*)(vp);
            vf[2 * t + 1] = *(const bf16x8*)(vp + 32);
        }
        float w4[4];
#pragma unroll
        for (int t = 0; t < 4; t++) w4[t] = fw[kt * 64 + t * 16 + l15] * 0.125f;

        // S tile = Q K^T (K regs prefetched last iteration)
        f32x4 sacc[4] = {};
#pragma unroll
        for (int t = 0; t < 4; t++) {
            sacc[t] = __builtin_amdgcn_mfma_f32_16x16x32_bf16(qf0, kf[2 * t],     sacc[t], 0, 0, 0);
            sacc[t] = __builtin_amdgcn_mfma_f32_16x16x32_bf16(qf1, kf[2 * t + 1], sacc[t], 0, 0, 0);
        }
        // prefetch next K tile while we do softmax
        if (kt + 1 < S_ / 64) {
#pragma unroll
            for (int t = 0; t < 4; t++) {
                const unsigned short* kp = Kbase + (long)((kt + 1) * 64 + t * 16) * DH_;
                kf[2 * t]     = *(const bf16x8*)(kp);
                kf[2 * t + 1] = *(const bf16x8*)(kp + 32);
            }
        }

        // p = exp(w*s) (no max subtraction needed; |w*s| < 0.1), accumulate l,
        // write P through per-wave LDS strip to convert C-layout -> A-layout
        unsigned short* pb = &P[kt & 1][wid][0];
#pragma unroll
        for (int t = 0; t < 4; t++)
#pragma unroll
            for (int r = 0; r < 4; r++) {
                float p = __expf(sacc[t][r] * w4[t]);
                l_r[r] += p;
                pb[(quad * 4 + r) * 72 + t * 16 + l15] = f2bf(p);
            }

        // O += P V
#pragma unroll
        for (int ks = 0; ks < 2; ks++) {
            bf16x8 pf = *(const bf16x8*)(pb + l15 * 72 + ks * 32 + quad * 8);
#pragma unroll
            for (int t = 0; t < 4; t++)
                oacc[t] = __builtin_amdgcn_mfma_f32_16x16x32_bf16(pf, vf[2 * t + ks], oacc[t], 0, 0, 0);
        }
    }

    // single end-of-kernel row-sum reduction (xor over the 16 lanes of the quad)
#pragma unroll
    for (int d = 1; d < 16; d <<= 1)
#pragma unroll
        for (int r = 0; r < 4; r++)
            l_r[r] += __shfl_xor(l_r[r], d);
    float inv[4];
#pragma unroll
    for (int r = 0; r < 4; r++) inv[r] = 1.0f / l_r[r];

    // epilogue: normalize, store O as [B, S, H*DV] bf16
    int b = bh >> 4, h = bh & 15;
#pragma unroll
    for (int t = 0; t < 4; t++)
#pragma unroll
        for (int r = 0; r < 4; r++) {
            int srow = qt * 64 + wid * 16 + quad * 4 + r;
            O[((long)(b * S_ + srow)) * 1024 + h * DH_ + t * 16 + l15] = f2bf(oacc[t][r] * inv[r]);
        }
}

// ---------------- launch ----------------

extern "C" void kernel_launch(void* const* d_in, const int* in_sizes, int n_in,
                              void* d_out, int out_size, void* d_ws, size_t ws_size,
                              hipStream_t stream)
{
    const float* x  = (const float*)d_in[0];
    const float* Wq = (const float*)d_in[1];
    const float* Wk = (const float*)d_in[2];
    const float* Wv = (const float*)d_in[3];
    const float* Wo = (const float*)d_in[4];
    const float* fw = (const float*)d_in[5];
    float* out = (float*)d_out;

    char* ws = (char*)d_ws;
    unsigned short* xb    = (unsigned short*)(ws);               // 8 MB   [B*S, D] bf16
    unsigned short* WqkvT = (unsigned short*)(ws + 8388608);     // 6 MB   [3072,1024] bf16 (transposed)
    unsigned short* WoT   = (unsigned short*)(ws + 14680064);    // 2 MB   [1024,1024] bf16 (transposed)
    unsigned short* Qb    = (unsigned short*)(ws + 16777216);    // 8 MB   [B,H,S,64]
    unsigned short* Kb    = (unsigned short*)(ws + 25165824);    // 8 MB   [B,H,S,64]
    unsigned short* Vt    = (unsigned short*)(ws + 33554432);    // 8 MB   [B,H,64,S]
    unsigned short* Ob    = xb;                                  // alias: xb dead after gemm1

    convert_x<<<dim3((B_ * S_ * D_) / 4 / 256), dim3(256), 0, stream>>>(x, xb, B_ * S_ * D_);
    transpose_w<<<dim3(32, 32, 4), dim3(32, 8), 0, stream>>>(
        Wq, Wk, Wv, Wo,
        WqkvT, WqkvT + 1024 * 1024, WqkvT + 2 * 1024 * 1024, WoT);
    gemm128<0><<<dim3(24, 32), dim3(256), 0, stream>>>(xb, WqkvT, Qb, Kb, Vt, (float*)nullptr);
    attn_kernel<<<dim3(S_ / 64, B_ * H_), dim3(256), 0, stream>>>(Qb, Kb, Vt, fw, Ob);
    gemm128<1><<<dim3(8, 32), dim3(256), 0, stream>>>(Ob, WoT,
        (unsigned short*)nullptr, (unsigned short*)nullptr, (unsigned short*)nullptr, out);
}

// Round 3
// 241.403 us; speedup vs baseline: 1.5841x; 1.5822x over previous
//
#include <hip/hip_runtime.h>
#include <hip/hip_bf16.h>
#include <stdint.h>

#define B_  2
#define S_  2048
#define D_  1024
#define H_  16
#define DH_ 64

typedef __attribute__((ext_vector_type(8))) __bf16 bf16x8;
typedef __attribute__((ext_vector_type(4))) float  f32x4;

__device__ inline unsigned short f2bf(float f) {
    union { float f; uint32_t u; } v; v.f = f;
    uint32_t r = (v.u + 0x7fffu + ((v.u >> 16) & 1u)) >> 16;
    return (unsigned short)r;
}

// async global->LDS, 16B per lane. LDS dest = wave-uniform base + lane*16;
// global src is per-lane (scatter allowed on the global side).
__device__ __forceinline__ void g2l16(const unsigned short* g, unsigned short* l) {
    __builtin_amdgcn_global_load_lds(
        (const __attribute__((address_space(1))) unsigned int*)g,
        (__attribute__((address_space(3))) unsigned int*)l,
        16, 0, 0);
}

// ---------------- conversion kernels ----------------

__global__ void convert_x(const float* __restrict__ x, unsigned short* __restrict__ xb, int n) {
    int i = (blockIdx.x * blockDim.x + threadIdx.x) * 4;
    if (i < n) {
        float4 v = *(const float4*)(x + i);
        ushort4 o;
        o.x = f2bf(v.x); o.y = f2bf(v.y); o.z = f2bf(v.z); o.w = f2bf(v.w);
        *(ushort4*)(xb + i) = o;
    }
}

// transpose+convert 1024x1024 fp32 [K][N] -> bf16 [N][K]; z selects matrix
__global__ void transpose_w(const float* __restrict__ s0, const float* __restrict__ s1,
                            const float* __restrict__ s2, const float* __restrict__ s3,
                            unsigned short* __restrict__ d0, unsigned short* __restrict__ d1,
                            unsigned short* __restrict__ d2, unsigned short* __restrict__ d3) {
    __shared__ float tile[32][33];
    const float* src; unsigned short* dst;
    switch (blockIdx.z) {
        case 0: src = s0; dst = d0; break;
        case 1: src = s1; dst = d1; break;
        case 2: src = s2; dst = d2; break;
        default: src = s3; dst = d3; break;
    }
    int n0 = blockIdx.x * 32, k0 = blockIdx.y * 32;
    int tx = threadIdx.x, ty = threadIdx.y;   // (32, 8)
    for (int j = 0; j < 32; j += 8)
        tile[ty + j][tx] = src[(long)(k0 + ty + j) * 1024 + n0 + tx];
    __syncthreads();
    for (int j = 0; j < 32; j += 8)
        dst[(long)(n0 + ty + j) * 1024 + k0 + tx] = f2bf(tile[tx][ty + j]);
}

// ---------------- 128x128 MFMA GEMM (unchanged this round) ----------------
template<int MODE>
__global__ __launch_bounds__(256, 2)
void gemm128(const unsigned short* __restrict__ A, const unsigned short* __restrict__ Bt,
             unsigned short* __restrict__ Qo, unsigned short* __restrict__ Ko,
             unsigned short* __restrict__ Vt, float* __restrict__ Cout)
{
    __shared__ unsigned short As[128 * 72];
    __shared__ unsigned short Bs[128 * 72];
    const int tid  = threadIdx.x;
    const int lane = tid & 63, wid = tid >> 6;
    const int quad = lane >> 4, l15 = lane & 15;
    const int wm = wid >> 1, wn = wid & 1;
    const int bm = blockIdx.y, bn = blockIdx.x;
    const int K = 1024;
    f32x4 acc[4][4] = {};
    const long Abase = (long)bm * 128 * K;
    const long Bbase = (long)bn * 128 * K;

    for (int k0 = 0; k0 < K; k0 += 64) {
        __syncthreads();
        for (int i = 0; i < 4; i++) {
            int c = tid + 256 * i;
            int row = c >> 3, cc = c & 7;
            uint4 va = *(const uint4*)(A + Abase + (long)row * K + k0 + cc * 8);
            *(uint4*)(As + row * 72 + cc * 8) = va;
            uint4 vb = *(const uint4*)(Bt + Bbase + (long)row * K + k0 + cc * 8);
            *(uint4*)(Bs + row * 72 + cc * 8) = vb;
        }
        __syncthreads();
        for (int ks = 0; ks < 2; ks++) {
            bf16x8 af[4], bfr[4];
            for (int t = 0; t < 4; t++) {
                af[t]  = *(const bf16x8*)(As + (wm * 64 + t * 16 + l15) * 72 + ks * 32 + quad * 8);
                bfr[t] = *(const bf16x8*)(Bs + (wn * 64 + t * 16 + l15) * 72 + ks * 32 + quad * 8);
            }
            for (int tm = 0; tm < 4; tm++)
                for (int tn = 0; tn < 4; tn++)
                    acc[tm][tn] = __builtin_amdgcn_mfma_f32_16x16x32_bf16(af[tm], bfr[tn], acc[tm][tn], 0, 0, 0);
        }
    }

    for (int tm = 0; tm < 4; tm++)
        for (int tn = 0; tn < 4; tn++)
            for (int r = 0; r < 4; r++) {
                int gm = bm * 128 + wm * 64 + tm * 16 + quad * 4 + r;
                int gn = bn * 128 + wn * 64 + tn * 16 + l15;
                float v = acc[tm][tn][r];
                if (MODE == 0) {
                    int b = gm >> 11, s = gm & 2047;
                    unsigned short bv = f2bf(v);
                    if (gn < 1024) {
                        int h = gn >> 6, d = gn & 63;
                        Qo[(((long)(b * H_ + h) * S_ + s) << 6) + d] = bv;
                    } else if (gn < 2048) {
                        int g = gn - 1024; int h = g >> 6, d = g & 63;
                        Ko[(((long)(b * H_ + h) * S_ + s) << 6) + d] = bv;
                    } else {
                        int g = gn - 2048; int h = g >> 6, d = g & 63;
                        Vt[((long)(b * H_ + h) * DH_ + d) * S_ + s] = bv;
                    }
                } else {
                    Cout[(long)gm * 1024 + gn] = v;
                }
            }
}

// ---------------- flash attention: global_load_lds double-buffered K/V ----------------
// grid (S/64, B*H), 256 threads = 4 waves, each wave owns 16 query rows.
// K tile (64 keys x 64d = 8 KB) and V tile (64d x 64 keys = 8 KB) are staged
// cooperatively via async global_load_lds (width 16, zero VGPR cost),
// double-buffered; the barrier that drains tile kt+1 comes one full compute
// phase after issue (m97 structure). Tiles are stored XOR-swizzled
// (16B-chunk index ^= row&7, applied on the per-lane GLOBAL address since the
// LDS side is lane-linear) so wave-wide ds_read_b128 fragment reads hit all
// 8 bank-groups evenly (minimum 8 phases for b128 = conflict-free).
// Softmax is max-free: fractal weights sum to 1 => |w*s| < ~0.1, exp safe.
__global__ __launch_bounds__(256, 2)
void attn_kernel(const unsigned short* __restrict__ Q, const unsigned short* __restrict__ Kb,
                 const unsigned short* __restrict__ Vt, const float* __restrict__ fw,
                 unsigned short* __restrict__ O)
{
    __shared__ __align__(16) unsigned short Ks[2][64 * 64];
    __shared__ __align__(16) unsigned short Vs[2][64 * 64];
    __shared__ __align__(16) unsigned short P[4][16 * 72];
    __shared__ float fws[2048];

    const int tid  = threadIdx.x;
    const int lane = tid & 63, wid = tid >> 6;
    const int quad = lane >> 4, l15 = lane & 15;
    const int bh = blockIdx.y;
    const int qt = blockIdx.x;

    const unsigned short* Kg = Kb + (long)bh * S_ * DH_;
    const unsigned short* Vg = Vt + (long)bh * (long)DH_ * S_;

    for (int i = tid; i < 2048; i += 256) fws[i] = fw[i] * 0.125f;

    const unsigned short* Qp = Q + ((long)bh * S_ + qt * 64 + wid * 16 + l15) * DH_ + quad * 8;
    bf16x8 qf0 = *(const bf16x8*)(Qp);
    bf16x8 qf1 = *(const bf16x8*)(Qp + 32);

    // stage tile kt into buffer buf (each wave stages its 16-row quarter of K and V)
    auto issue = [&](int buf, int kt) {
#pragma unroll
        for (int i = 0; i < 2; i++) {
            int slot = wid * 128 + i * 64 + lane;           // LDS 16B-chunk index
            int row = slot >> 3, cp = slot & 7;
            int c = cp ^ (row & 7);                         // global chunk (deswizzle)
            g2l16(Kg + ((long)(kt * 64 + row) * 64 + c * 8),
                  &Ks[buf][(wid * 128 + i * 64) * 8]);
        }
#pragma unroll
        for (int i = 0; i < 2; i++) {
            int slot = wid * 128 + i * 64 + lane;
            int row = slot >> 3, cp = slot & 7;
            int c = cp ^ (row & 7);
            g2l16(Vg + ((long)row * S_ + kt * 64 + c * 8),
                  &Vs[buf][(wid * 128 + i * 64) * 8]);
        }
    };

    f32x4 oacc[4] = {};
    float l_r[4] = {0.f, 0.f, 0.f, 0.f};

    issue(0, 0);
    __syncthreads();   // tile 0 + fws ready

    for (int kt = 0; kt < S_ / 64; kt++) {
        const int cur = kt & 1;
        if (kt + 1 < S_ / 64) issue(1 - cur, kt + 1);   // async, drained at end-of-iter barrier

        const unsigned short* Kc = &Ks[cur][0];
        const unsigned short* Vc = &Vs[cur][0];

        // ---- S tile = Q K^T (swizzled b128 reads from LDS) ----
        f32x4 sacc[4] = {};
#pragma unroll
        for (int t = 0; t < 4; t++) {
            int row = t * 16 + l15;
            bf16x8 k0 = *(const bf16x8*)(Kc + (row * 8 + (quad       ^ (l15 & 7))) * 8);
            bf16x8 k1 = *(const bf16x8*)(Kc + (row * 8 + ((4 + quad) ^ (l15 & 7))) * 8);
            sacc[t] = __builtin_amdgcn_mfma_f32_16x16x32_bf16(qf0, k0, sacc[t], 0, 0, 0);
            sacc[t] = __builtin_amdgcn_mfma_f32_16x16x32_bf16(qf1, k1, sacc[t], 0, 0, 0);
        }

        float w4[4];
#pragma unroll
        for (int t = 0; t < 4; t++) w4[t] = fws[kt * 64 + t * 16 + l15];

        // ---- p = exp(w*s), accumulate l, C-layout -> A-layout via per-wave P strip ----
        unsigned short* pb = &P[wid][0];
#pragma unroll
        for (int t = 0; t < 4; t++)
#pragma unroll
            for (int r = 0; r < 4; r++) {
                float p = __expf(sacc[t][r] * w4[t]);
                l_r[r] += p;
                pb[(quad * 4 + r) * 72 + t * 16 + l15] = f2bf(p);
            }

        // ---- O += P V ----
#pragma unroll
        for (int ks = 0; ks < 2; ks++) {
            bf16x8 pf = *(const bf16x8*)(pb + l15 * 72 + ks * 32 + quad * 8);
#pragma unroll
            for (int t = 0; t < 4; t++) {
                int row = t * 16 + l15;
                bf16x8 vf = *(const bf16x8*)(Vc + (row * 8 + ((ks * 4 + quad) ^ (l15 & 7))) * 8);
                oacc[t] = __builtin_amdgcn_mfma_f32_16x16x32_bf16(pf, vf, oacc[t], 0, 0, 0);
            }
        }

        __syncthreads();   // all waves done with buf[cur]; tile kt+1 drained & visible
    }

    // single end-of-kernel row-sum reduction
#pragma unroll
    for (int d = 1; d < 16; d <<= 1)
#pragma unroll
        for (int r = 0; r < 4; r++)
            l_r[r] += __shfl_xor(l_r[r], d);
    float inv[4];
#pragma unroll
    for (int r = 0; r < 4; r++) inv[r] = 1.0f / l_r[r];

    int b = bh >> 4, h = bh & 15;
#pragma unroll
    for (int t = 0; t < 4; t++)
#pragma unroll
        for (int r = 0; r < 4; r++) {
            int srow = qt * 64 + wid * 16 + quad * 4 + r;
            O[((long)(b * S_ + srow)) * 1024 + h * DH_ + t * 16 + l15] = f2bf(oacc[t][r] * inv[r]);
        }
}

// ---------------- launch ----------------

extern "C" void kernel_launch(void* const* d_in, const int* in_sizes, int n_in,
                              void* d_out, int out_size, void* d_ws, size_t ws_size,
                              hipStream_t stream)
{
    const float* x  = (const float*)d_in[0];
    const float* Wq = (const float*)d_in[1];
    const float* Wk = (const float*)d_in[2];
    const float* Wv = (const float*)d_in[3];
    const float* Wo = (const float*)d_in[4];
    const float* fw = (const float*)d_in[5];
    float* out = (float*)d_out;

    char* ws = (char*)d_ws;
    unsigned short* xb    = (unsigned short*)(ws);               // 8 MB   [B*S, D] bf16
    unsigned short* WqkvT = (unsigned short*)(ws + 8388608);     // 6 MB   [3072,1024] bf16 (transposed)
    unsigned short* WoT   = (unsigned short*)(ws + 14680064);    // 2 MB   [1024,1024] bf16 (transposed)
    unsigned short* Qb    = (unsigned short*)(ws + 16777216);    // 8 MB   [B,H,S,64]
    unsigned short* Kb    = (unsigned short*)(ws + 25165824);    // 8 MB   [B,H,S,64]
    unsigned short* Vt    = (unsigned short*)(ws + 33554432);    // 8 MB   [B,H,64,S]
    unsigned short* Ob    = xb;                                  // alias: xb dead after gemm1

    convert_x<<<dim3((B_ * S_ * D_) / 4 / 256), dim3(256), 0, stream>>>(x, xb, B_ * S_ * D_);
    transpose_w<<<dim3(32, 32, 4), dim3(32, 8), 0, stream>>>(
        Wq, Wk, Wv, Wo,
        WqkvT, WqkvT + 1024 * 1024, WqkvT + 2 * 1024 * 1024, WoT);
    gemm128<0><<<dim3(24, 32), dim3(256), 0, stream>>>(xb, WqkvT, Qb, Kb, Vt, (float*)nullptr);
    attn_kernel<<<dim3(S_ / 64, B_ * H_), dim3(256), 0, stream>>>(Qb, Kb, Vt, fw, Ob);
    gemm128<1><<<dim3(8, 32), dim3(256), 0, stream>>>(Ob, WoT,
        (unsigned short*)nullptr, (unsigned short*)nullptr, (unsigned short*)nullptr, out);
}

// Round 4
// 232.302 us; speedup vs baseline: 1.6462x; 1.0392x over previous
//
#include <hip/hip_runtime.h>
#include <hip/hip_bf16.h>
#include <stdint.h>

#define B_  2
#define S_  2048
#define D_  1024
#define H_  16
#define DH_ 64

typedef __attribute__((ext_vector_type(8))) __bf16 bf16x8;
typedef __attribute__((ext_vector_type(4))) float  f32x4;

__device__ inline unsigned short f2bf(float f) {
    union { float f; uint32_t u; } v; v.f = f;
    uint32_t r = (v.u + 0x7fffu + ((v.u >> 16) & 1u)) >> 16;
    return (unsigned short)r;
}

// async global->LDS, 16B per lane. LDS dest = wave-uniform base + lane*16.
__device__ __forceinline__ void g2l16(const unsigned short* g, unsigned short* l) {
    __builtin_amdgcn_global_load_lds(
        (const __attribute__((address_space(1))) unsigned int*)g,
        (__attribute__((address_space(3))) unsigned int*)l,
        16, 0, 0);
}

// ---------------- conversion kernels ----------------

__global__ void convert_x(const float* __restrict__ x, unsigned short* __restrict__ xb, int n) {
    int i = (blockIdx.x * blockDim.x + threadIdx.x) * 4;
    if (i < n) {
        float4 v = *(const float4*)(x + i);
        ushort4 o;
        o.x = f2bf(v.x); o.y = f2bf(v.y); o.z = f2bf(v.z); o.w = f2bf(v.w);
        *(ushort4*)(xb + i) = o;
    }
}

// transpose+convert 1024x1024 fp32 [K][N] -> bf16 [N][K]; z selects matrix
__global__ void transpose_w(const float* __restrict__ s0, const float* __restrict__ s1,
                            const float* __restrict__ s2, const float* __restrict__ s3,
                            unsigned short* __restrict__ d0, unsigned short* __restrict__ d1,
                            unsigned short* __restrict__ d2, unsigned short* __restrict__ d3) {
    __shared__ float tile[32][33];
    const float* src; unsigned short* dst;
    switch (blockIdx.z) {
        case 0: src = s0; dst = d0; break;
        case 1: src = s1; dst = d1; break;
        case 2: src = s2; dst = d2; break;
        default: src = s3; dst = d3; break;
    }
    int n0 = blockIdx.x * 32, k0 = blockIdx.y * 32;
    int tx = threadIdx.x, ty = threadIdx.y;   // (32, 8)
    for (int j = 0; j < 32; j += 8)
        tile[ty + j][tx] = src[(long)(k0 + ty + j) * 1024 + n0 + tx];
    __syncthreads();
    for (int j = 0; j < 32; j += 8)
        dst[(long)(n0 + ty + j) * 1024 + k0 + tx] = f2bf(tile[tx][ty + j]);
}

// ---------------- 128x128 MFMA GEMM, m97-style global_load_lds staging ----------------
// A [M,1024] bf16 row-major; Bt [N,1024] bf16 row-major.
// LDS tiles 128x64 bf16, XOR-swizzled (16B chunk ^= row&7) for conflict-free b128.
// MODE 0: scatter epilogue -> Q[B,H,S,64], K[B,H,S,64], Vt[B,H,64,S] (bf16)
// MODE 1: C fp32 [M,1024] row-major
template<int MODE>
__global__ __launch_bounds__(256, 2)
void gemm128(const unsigned short* __restrict__ A, const unsigned short* __restrict__ Bt,
             unsigned short* __restrict__ Qo, unsigned short* __restrict__ Ko,
             unsigned short* __restrict__ Vt, float* __restrict__ Cout)
{
    __shared__ __align__(16) unsigned short As[128 * 64];
    __shared__ __align__(16) unsigned short Bs[128 * 64];
    const int tid  = threadIdx.x;
    const int lane = tid & 63, wid = tid >> 6;
    const int quad = lane >> 4, l15 = lane & 15;
    const int wm = wid >> 1, wn = wid & 1;
    const int bm = blockIdx.y, bn = blockIdx.x;
    const int K = 1024;
    f32x4 acc[4][4] = {};
    const long Abase = (long)bm * 128 * K;
    const long Bbase = (long)bn * 128 * K;

    for (int k0 = 0; k0 < K; k0 += 64) {
        __syncthreads();   // previous tile's LDS reads done
#pragma unroll
        for (int i = 0; i < 4; i++) {
            int slot = i * 256 + wid * 64 + lane;        // 16B-chunk id, 0..1023
            int row = slot >> 3, cp = slot & 7;
            int c = cp ^ (row & 7);                      // deswizzle on global side
            g2l16(A + Abase + (long)row * K + k0 + c * 8, &As[(i * 256 + wid * 64) * 8]);
        }
#pragma unroll
        for (int i = 0; i < 4; i++) {
            int slot = i * 256 + wid * 64 + lane;
            int row = slot >> 3, cp = slot & 7;
            int c = cp ^ (row & 7);
            g2l16(Bt + Bbase + (long)row * K + k0 + c * 8, &Bs[(i * 256 + wid * 64) * 8]);
        }
        __syncthreads();   // vmcnt drained -> tile visible
#pragma unroll
        for (int ks = 0; ks < 2; ks++) {
            bf16x8 af[4], bfr[4];
#pragma unroll
            for (int t = 0; t < 4; t++) {
                int ra = wm * 64 + t * 16 + l15;
                af[t]  = *(const bf16x8*)(As + ra * 64 + (((ks * 4 + quad) ^ (l15 & 7))) * 8);
                int rb = wn * 64 + t * 16 + l15;
                bfr[t] = *(const bf16x8*)(Bs + rb * 64 + (((ks * 4 + quad) ^ (l15 & 7))) * 8);
            }
#pragma unroll
            for (int tm = 0; tm < 4; tm++)
#pragma unroll
                for (int tn = 0; tn < 4; tn++)
                    acc[tm][tn] = __builtin_amdgcn_mfma_f32_16x16x32_bf16(af[tm], bfr[tn], acc[tm][tn], 0, 0, 0);
        }
    }

    for (int tm = 0; tm < 4; tm++)
        for (int tn = 0; tn < 4; tn++)
            for (int r = 0; r < 4; r++) {
                int gm = bm * 128 + wm * 64 + tm * 16 + quad * 4 + r;
                int gn = bn * 128 + wn * 64 + tn * 16 + l15;
                float v = acc[tm][tn][r];
                if (MODE == 0) {
                    int b = gm >> 11, s = gm & 2047;
                    unsigned short bv = f2bf(v);
                    if (gn < 1024) {
                        int h = gn >> 6, d = gn & 63;
                        Qo[(((long)(b * H_ + h) * S_ + s) << 6) + d] = bv;
                    } else if (gn < 2048) {
                        int g = gn - 1024; int h = g >> 6, d = g & 63;
                        Ko[(((long)(b * H_ + h) * S_ + s) << 6) + d] = bv;
                    } else {
                        int g = gn - 2048; int h = g >> 6, d = g & 63;
                        Vt[((long)(b * H_ + h) * DH_ + d) * S_ + s] = bv;
                    }
                } else {
                    Cout[(long)gm * 1024 + gn] = v;
                }
            }
}

// ---------------- flash attention: 32 q-rows/wave, double-buffered K/V ----------------
// grid (S/128, B*H), 256 threads = 4 waves, each wave owns 32 query rows (2 strips).
// K/V tiles staged via global_load_lds (XOR-swizzled); each K/V b128 read now
// feeds 2x the MFMA (both q-strips) -> halves LDS traffic per FLOP vs R2.
// fw read from global (VMEM pipe, L1-hot) - off the LDS pipe entirely.
// Softmax max-free (fractal weights sum to 1 => |w*s| < ~0.1); p = exp2(s * w')
// with w' = fw * 0.125 * log2(e) - exact same value, one fewer mul, native v_exp.
__global__ __launch_bounds__(256, 2)
void attn_kernel(const unsigned short* __restrict__ Q, const unsigned short* __restrict__ Kb,
                 const unsigned short* __restrict__ Vt, const float* __restrict__ fw,
                 unsigned short* __restrict__ O)
{
    __shared__ __align__(16) unsigned short Ks[2][64 * 64];
    __shared__ __align__(16) unsigned short Vs[2][64 * 64];
    __shared__ __align__(16) unsigned short P[4][32 * 72];

    const int tid  = threadIdx.x;
    const int lane = tid & 63, wid = tid >> 6;
    const int quad = lane >> 4, l15 = lane & 15;
    const int bh = blockIdx.y;
    const int qt = blockIdx.x;

    const unsigned short* Kg = Kb + (long)bh * S_ * DH_;
    const unsigned short* Vg = Vt + (long)bh * (long)DH_ * S_;

    bf16x8 qf[2][2];
#pragma unroll
    for (int s = 0; s < 2; s++) {
        const unsigned short* Qp = Q + ((long)bh * S_ + qt * 128 + wid * 32 + s * 16 + l15) * DH_ + quad * 8;
        qf[s][0] = *(const bf16x8*)(Qp);
        qf[s][1] = *(const bf16x8*)(Qp + 32);
    }

    auto issue = [&](int buf, int kt) {
#pragma unroll
        for (int i = 0; i < 2; i++) {
            int slot = wid * 128 + i * 64 + lane;
            int row = slot >> 3, cp = slot & 7;
            int c = cp ^ (row & 7);
            g2l16(Kg + ((long)(kt * 64 + row) * 64 + c * 8), &Ks[buf][(wid * 128 + i * 64) * 8]);
        }
#pragma unroll
        for (int i = 0; i < 2; i++) {
            int slot = wid * 128 + i * 64 + lane;
            int row = slot >> 3, cp = slot & 7;
            int c = cp ^ (row & 7);
            g2l16(Vg + ((long)row * S_ + kt * 64 + c * 8), &Vs[buf][(wid * 128 + i * 64) * 8]);
        }
    };

    f32x4 oacc[2][4] = {};
    float l_r[2][4] = {};

    issue(0, 0);
    __syncthreads();

    const float C = 0.125f * 1.44269504f;   // score scale * log2(e)
    for (int kt = 0; kt < S_ / 64; kt++) {
        const int cur = kt & 1;
        if (kt + 1 < S_ / 64) issue(1 - cur, kt + 1);

        float w4[4];
#pragma unroll
        for (int t = 0; t < 4; t++) w4[t] = fw[kt * 64 + t * 16 + l15] * C;

        const unsigned short* Kc = &Ks[cur][0];
        const unsigned short* Vc = &Vs[cur][0];

        // ---- S tiles: both q-strips share each K fragment read ----
        f32x4 sacc[2][4] = {};
#pragma unroll
        for (int t = 0; t < 4; t++) {
            int row = t * 16 + l15;
            bf16x8 k0 = *(const bf16x8*)(Kc + (row * 8 + (quad       ^ (l15 & 7))) * 8);
            bf16x8 k1 = *(const bf16x8*)(Kc + (row * 8 + ((4 + quad) ^ (l15 & 7))) * 8);
#pragma unroll
            for (int s = 0; s < 2; s++) {
                sacc[s][t] = __builtin_amdgcn_mfma_f32_16x16x32_bf16(qf[s][0], k0, sacc[s][t], 0, 0, 0);
                sacc[s][t] = __builtin_amdgcn_mfma_f32_16x16x32_bf16(qf[s][1], k1, sacc[s][t], 0, 0, 0);
            }
        }

        // ---- p = 2^(s*w'), accumulate l, C-layout -> A-layout via per-wave P strip ----
        unsigned short* pb = &P[wid][0];
#pragma unroll
        for (int s = 0; s < 2; s++)
#pragma unroll
            for (int t = 0; t < 4; t++)
#pragma unroll
                for (int r = 0; r < 4; r++) {
                    float p = exp2f(sacc[s][t][r] * w4[t]);
                    l_r[s][r] += p;
                    pb[(s * 16 + quad * 4 + r) * 72 + t * 16 + l15] = f2bf(p);
                }

        // ---- O += P V: both strips share each V fragment read ----
#pragma unroll
        for (int ks = 0; ks < 2; ks++) {
            bf16x8 pf0 = *(const bf16x8*)(pb + l15 * 72 + ks * 32 + quad * 8);
            bf16x8 pf1 = *(const bf16x8*)(pb + (16 + l15) * 72 + ks * 32 + quad * 8);
#pragma unroll
            for (int t = 0; t < 4; t++) {
                int row = t * 16 + l15;
                bf16x8 vf = *(const bf16x8*)(Vc + (row * 8 + ((ks * 4 + quad) ^ (l15 & 7))) * 8);
                oacc[0][t] = __builtin_amdgcn_mfma_f32_16x16x32_bf16(pf0, vf, oacc[0][t], 0, 0, 0);
                oacc[1][t] = __builtin_amdgcn_mfma_f32_16x16x32_bf16(pf1, vf, oacc[1][t], 0, 0, 0);
            }
        }

        __syncthreads();   // all waves done with buf[cur]; next tile drained & visible
    }

    // end-of-kernel row-sum reductions (within each 16-lane quad group)
#pragma unroll
    for (int s = 0; s < 2; s++)
#pragma unroll
        for (int d = 1; d < 16; d <<= 1)
#pragma unroll
            for (int r = 0; r < 4; r++)
                l_r[s][r] += __shfl_xor(l_r[s][r], d);

    int b = bh >> 4, h = bh & 15;
#pragma unroll
    for (int s = 0; s < 2; s++)
#pragma unroll
        for (int r = 0; r < 4; r++) {
            float inv = 1.0f / l_r[s][r];
            int srow = qt * 128 + wid * 32 + s * 16 + quad * 4 + r;
#pragma unroll
            for (int t = 0; t < 4; t++)
                O[((long)(b * S_ + srow)) * 1024 + h * DH_ + t * 16 + l15] = f2bf(oacc[s][t][r] * inv);
        }
}

// ---------------- launch ----------------

extern "C" void kernel_launch(void* const* d_in, const int* in_sizes, int n_in,
                              void* d_out, int out_size, void* d_ws, size_t ws_size,
                              hipStream_t stream)
{
    const float* x  = (const float*)d_in[0];
    const float* Wq = (const float*)d_in[1];
    const float* Wk = (const float*)d_in[2];
    const float* Wv = (const float*)d_in[3];
    const float* Wo = (const float*)d_in[4];
    const float* fw = (const float*)d_in[5];
    float* out = (float*)d_out;

    char* ws = (char*)d_ws;
    unsigned short* xb    = (unsigned short*)(ws);               // 8 MB   [B*S, D] bf16
    unsigned short* WqkvT = (unsigned short*)(ws + 8388608);     // 6 MB   [3072,1024] bf16 (transposed)
    unsigned short* WoT   = (unsigned short*)(ws + 14680064);    // 2 MB   [1024,1024] bf16 (transposed)
    unsigned short* Qb    = (unsigned short*)(ws + 16777216);    // 8 MB   [B,H,S,64]
    unsigned short* Kb    = (unsigned short*)(ws + 25165824);    // 8 MB   [B,H,S,64]
    unsigned short* Vt    = (unsigned short*)(ws + 33554432);    // 8 MB   [B,H,64,S]
    unsigned short* Ob    = xb;                                  // alias: xb dead after gemm1

    convert_x<<<dim3((B_ * S_ * D_) / 4 / 256), dim3(256), 0, stream>>>(x, xb, B_ * S_ * D_);
    transpose_w<<<dim3(32, 32, 4), dim3(32, 8), 0, stream>>>(
        Wq, Wk, Wv, Wo,
        WqkvT, WqkvT + 1024 * 1024, WqkvT + 2 * 1024 * 1024, WoT);
    gemm128<0><<<dim3(24, 32), dim3(256), 0, stream>>>(xb, WqkvT, Qb, Kb, Vt, (float*)nullptr);
    attn_kernel<<<dim3(S_ / 128, B_ * H_), dim3(256), 0, stream>>>(Qb, Kb, Vt, fw, Ob);
    gemm128<1><<<dim3(8, 32), dim3(256), 0, stream>>>(Ob, WoT,
        (unsigned short*)nullptr, (unsigned short*)nullptr, (unsigned short*)nullptr, out);
}

// Round 6
// 218.947 us; speedup vs baseline: 1.7466x; 1.0610x over previous
//
#include <hip/hip_runtime.h>
#include <hip/hip_bf16.h>
#include <stdint.h>

#define B_  2
#define S_  2048
#define D_  1024
#define H_  16
#define DH_ 64

typedef __attribute__((ext_vector_type(8))) __bf16    bf16x8;
typedef __attribute__((ext_vector_type(8))) _Float16  f16x8;
typedef __attribute__((ext_vector_type(2))) __fp16    fp16x2;   // cvt_pkrtz return type
typedef __attribute__((ext_vector_type(4))) float     f32x4;

__device__ inline unsigned short f2bf(float f) {
    union { float f; uint32_t u; } v; v.f = f;
    uint32_t r = (v.u + 0x7fffu + ((v.u >> 16) & 1u)) >> 16;
    return (unsigned short)r;
}

// async global->LDS, 16B per lane. LDS dest = wave-uniform base + lane*16.
__device__ __forceinline__ void g2l16(const unsigned short* g, unsigned short* l) {
    __builtin_amdgcn_global_load_lds(
        (const __attribute__((address_space(1))) unsigned int*)g,
        (__attribute__((address_space(3))) unsigned int*)l,
        16, 0, 0);
}

// ---------------- conversion kernels ----------------

__global__ void convert_x(const float* __restrict__ x, unsigned short* __restrict__ xb, int n) {
    int i = (blockIdx.x * blockDim.x + threadIdx.x) * 4;
    if (i < n) {
        float4 v = *(const float4*)(x + i);
        ushort4 o;
        o.x = f2bf(v.x); o.y = f2bf(v.y); o.z = f2bf(v.z); o.w = f2bf(v.w);
        *(ushort4*)(xb + i) = o;
    }
}

// transpose+convert 1024x1024 fp32 [K][N] -> bf16 [N][K]; z selects matrix
__global__ void transpose_w(const float* __restrict__ s0, const float* __restrict__ s1,
                            const float* __restrict__ s2, const float* __restrict__ s3,
                            unsigned short* __restrict__ d0, unsigned short* __restrict__ d1,
                            unsigned short* __restrict__ d2, unsigned short* __restrict__ d3) {
    __shared__ float tile[32][33];
    const float* src; unsigned short* dst;
    switch (blockIdx.z) {
        case 0: src = s0; dst = d0; break;
        case 1: src = s1; dst = d1; break;
        case 2: src = s2; dst = d2; break;
        default: src = s3; dst = d3; break;
    }
    int n0 = blockIdx.x * 32, k0 = blockIdx.y * 32;
    int tx = threadIdx.x, ty = threadIdx.y;   // (32, 8)
    for (int j = 0; j < 32; j += 8)
        tile[ty + j][tx] = src[(long)(k0 + ty + j) * 1024 + n0 + tx];
    __syncthreads();
    for (int j = 0; j < 32; j += 8)
        dst[(long)(n0 + ty + j) * 1024 + k0 + tx] = f2bf(tile[tx][ty + j]);
}

// ---------------- 128x128 MFMA GEMM, global_load_lds staging ----------------
// MODE 0: scatter epilogue -> Q[B,H,S,64] bf16, K[B,H,S,64] bf16, Vt[B,H,64,S] FP16
// MODE 1: C fp32 [M,1024] row-major
template<int MODE>
__global__ __launch_bounds__(256, 2)
void gemm128(const unsigned short* __restrict__ A, const unsigned short* __restrict__ Bt,
             unsigned short* __restrict__ Qo, unsigned short* __restrict__ Ko,
             unsigned short* __restrict__ Vt, float* __restrict__ Cout)
{
    __shared__ __align__(16) unsigned short As[128 * 64];
    __shared__ __align__(16) unsigned short Bs[128 * 64];
    const int tid  = threadIdx.x;
    const int lane = tid & 63, wid = tid >> 6;
    const int quad = lane >> 4, l15 = lane & 15;
    const int wm = wid >> 1, wn = wid & 1;
    const int bm = blockIdx.y, bn = blockIdx.x;
    const int K = 1024;
    f32x4 acc[4][4] = {};
    const long Abase = (long)bm * 128 * K;
    const long Bbase = (long)bn * 128 * K;

    for (int k0 = 0; k0 < K; k0 += 64) {
        __syncthreads();
#pragma unroll
        for (int i = 0; i < 4; i++) {
            int slot = i * 256 + wid * 64 + lane;
            int row = slot >> 3, cp = slot & 7;
            int c = cp ^ (row & 7);
            g2l16(A + Abase + (long)row * K + k0 + c * 8, &As[(i * 256 + wid * 64) * 8]);
        }
#pragma unroll
        for (int i = 0; i < 4; i++) {
            int slot = i * 256 + wid * 64 + lane;
            int row = slot >> 3, cp = slot & 7;
            int c = cp ^ (row & 7);
            g2l16(Bt + Bbase + (long)row * K + k0 + c * 8, &Bs[(i * 256 + wid * 64) * 8]);
        }
        __syncthreads();
#pragma unroll
        for (int ks = 0; ks < 2; ks++) {
            bf16x8 af[4], bfr[4];
#pragma unroll
            for (int t = 0; t < 4; t++) {
                int ra = wm * 64 + t * 16 + l15;
                af[t]  = *(const bf16x8*)(As + ra * 64 + (((ks * 4 + quad) ^ (l15 & 7))) * 8);
                int rb = wn * 64 + t * 16 + l15;
                bfr[t] = *(const bf16x8*)(Bs + rb * 64 + (((ks * 4 + quad) ^ (l15 & 7))) * 8);
            }
#pragma unroll
            for (int tm = 0; tm < 4; tm++)
#pragma unroll
                for (int tn = 0; tn < 4; tn++)
                    acc[tm][tn] = __builtin_amdgcn_mfma_f32_16x16x32_bf16(af[tm], bfr[tn], acc[tm][tn], 0, 0, 0);
        }
    }

    for (int tm = 0; tm < 4; tm++)
        for (int tn = 0; tn < 4; tn++)
            for (int r = 0; r < 4; r++) {
                int gm = bm * 128 + wm * 64 + tm * 16 + quad * 4 + r;
                int gn = bn * 128 + wn * 64 + tn * 16 + l15;
                float v = acc[tm][tn][r];
                if (MODE == 0) {
                    int b = gm >> 11, s = gm & 2047;
                    if (gn < 1024) {
                        int h = gn >> 6, d = gn & 63;
                        Qo[(((long)(b * H_ + h) * S_ + s) << 6) + d] = f2bf(v);
                    } else if (gn < 2048) {
                        int g = gn - 1024; int h = g >> 6, d = g & 63;
                        Ko[(((long)(b * H_ + h) * S_ + s) << 6) + d] = f2bf(v);
                    } else {
                        int g = gn - 2048; int h = g >> 6, d = g & 63;
                        union { _Float16 h; unsigned short u; } cv;
                        cv.h = (_Float16)v;                       // V^T stored FP16
                        Vt[((long)(b * H_ + h) * DH_ + d) * S_ + s] = cv.u;
                    }
                } else {
                    Cout[(long)gm * 1024 + gn] = v;
                }
            }
}

// ---------------- flash attention: S^T trick + fp16 P/V ----------------
// grid (S/128, B*H), 256 threads = 4 waves, 32 q-rows/wave.
// S^T = mfma(K_frag, Q_frag): same LDS/register loads as Q*K^T but the
// accumulator comes out transposed (row=key=quad*4+r, col=qrow=l15). Each
// lane's 4 acc regs are 4 CONSECUTIVE KEYS (the k-dim of PV), so P packs via
// v_cvt_pkrtz (2 vals/inst, fp16) and writes as 8 b64 stores (conflict-free)
// instead of 64 scattered b16 (the old 2^20-conflict source). PV runs
// mfma_f32_16x16x32_f16 with V^T staged in fp16. l is per-qrow scalar.
// Softmax max-free: fractal weights sum to 1 => |w*s| < ~0.1.
__global__ __launch_bounds__(256, 3)
void attn_kernel(const unsigned short* __restrict__ Q, const unsigned short* __restrict__ Kb,
                 const unsigned short* __restrict__ Vt, const float* __restrict__ fw,
                 unsigned short* __restrict__ O)
{
    __shared__ __align__(16) unsigned short Ks[2][64 * 64];
    __shared__ __align__(16) unsigned short Vs[2][64 * 64];
    __shared__ __align__(16) unsigned short P[4][32 * 72];   // fp16 bits, row=qrow, col=key

    const int tid  = threadIdx.x;
    const int lane = tid & 63, wid = tid >> 6;
    const int quad = lane >> 4, l15 = lane & 15;
    const int bh = blockIdx.y;
    const int qt = blockIdx.x;

    const unsigned short* Kg = Kb + (long)bh * S_ * DH_;
    const unsigned short* Vg = Vt + (long)bh * (long)DH_ * S_;

    bf16x8 qf[2][2];
#pragma unroll
    for (int s = 0; s < 2; s++) {
        const unsigned short* Qp = Q + ((long)bh * S_ + qt * 128 + wid * 32 + s * 16 + l15) * DH_ + quad * 8;
        qf[s][0] = *(const bf16x8*)(Qp);
        qf[s][1] = *(const bf16x8*)(Qp + 32);
    }

    auto issue = [&](int buf, int kt) {
#pragma unroll
        for (int i = 0; i < 2; i++) {
            int slot = wid * 128 + i * 64 + lane;
            int row = slot >> 3, cp = slot & 7;
            int c = cp ^ (row & 7);
            g2l16(Kg + ((long)(kt * 64 + row) * 64 + c * 8), &Ks[buf][(wid * 128 + i * 64) * 8]);
        }
#pragma unroll
        for (int i = 0; i < 2; i++) {
            int slot = wid * 128 + i * 64 + lane;
            int row = slot >> 3, cp = slot & 7;
            int c = cp ^ (row & 7);
            g2l16(Vg + ((long)row * S_ + kt * 64 + c * 8), &Vs[buf][(wid * 128 + i * 64) * 8]);
        }
    };

    f32x4 oacc[2][4] = {};
    float l_r[2] = {0.f, 0.f};

    issue(0, 0);
    __syncthreads();

    const float C = 0.125f * 1.44269504f;   // score scale * log2(e)
    for (int kt = 0; kt < S_ / 64; kt++) {
        const int cur = kt & 1;
        if (kt + 1 < S_ / 64) issue(1 - cur, kt + 1);

        // per-key fractal weights: this lane's 4 consecutive keys per t-tile
        f32x4 wvc[4];
#pragma unroll
        for (int t = 0; t < 4; t++) {
            float4 w = *(const float4*)(fw + kt * 64 + t * 16 + quad * 4);
            wvc[t][0] = w.x * C; wvc[t][1] = w.y * C; wvc[t][2] = w.z * C; wvc[t][3] = w.w * C;
        }

        const unsigned short* Kc = &Ks[cur][0];
        const unsigned short* Vc = &Vs[cur][0];

        // ---- S^T tiles: mfma(K_frag, Q_frag) -> row=key(quad*4+r), col=qrow(l15) ----
        f32x4 sacc[2][4] = {};
#pragma unroll
        for (int t = 0; t < 4; t++) {
            int row = t * 16 + l15;
            bf16x8 k0 = *(const bf16x8*)(Kc + (row * 8 + (quad       ^ (l15 & 7))) * 8);
            bf16x8 k1 = *(const bf16x8*)(Kc + (row * 8 + ((4 + quad) ^ (l15 & 7))) * 8);
#pragma unroll
            for (int s = 0; s < 2; s++) {
                sacc[s][t] = __builtin_amdgcn_mfma_f32_16x16x32_bf16(k0, qf[s][0], sacc[s][t], 0, 0, 0);
                sacc[s][t] = __builtin_amdgcn_mfma_f32_16x16x32_bf16(k1, qf[s][1], sacc[s][t], 0, 0, 0);
            }
        }

        // ---- p = 2^(s*w'); packed fp16 P write (b64, conflict-free) ----
        unsigned short* pb = &P[wid][0];
#pragma unroll
        for (int s = 0; s < 2; s++) {
#pragma unroll
            for (int t = 0; t < 4; t++) {
                float p0 = exp2f(sacc[s][t][0] * wvc[t][0]);
                float p1 = exp2f(sacc[s][t][1] * wvc[t][1]);
                float p2 = exp2f(sacc[s][t][2] * wvc[t][2]);
                float p3 = exp2f(sacc[s][t][3] * wvc[t][3]);
                l_r[s] += (p0 + p1) + (p2 + p3);
                union { fp16x2 h; unsigned int u; } a, b;
                a.h = __builtin_amdgcn_cvt_pkrtz(p0, p1);
                b.h = __builtin_amdgcn_cvt_pkrtz(p2, p3);
                *(uint2*)(pb + (s * 16 + l15) * 72 + t * 16 + quad * 4) = make_uint2(a.u, b.u);
            }
        }

        // ---- O += P V (fp16 mfma); both strips share each V fragment read ----
#pragma unroll
        for (int ks = 0; ks < 2; ks++) {
            f16x8 pf0 = *(const f16x8*)(pb + l15 * 72 + ks * 32 + quad * 8);
            f16x8 pf1 = *(const f16x8*)(pb + (16 + l15) * 72 + ks * 32 + quad * 8);
#pragma unroll
            for (int t = 0; t < 4; t++) {
                int row = t * 16 + l15;
                f16x8 vf = *(const f16x8*)(Vc + (row * 8 + ((ks * 4 + quad) ^ (l15 & 7))) * 8);
                oacc[0][t] = __builtin_amdgcn_mfma_f32_16x16x32_f16(pf0, vf, oacc[0][t], 0, 0, 0);
                oacc[1][t] = __builtin_amdgcn_mfma_f32_16x16x32_f16(pf1, vf, oacc[1][t], 0, 0, 0);
            }
        }

        __syncthreads();
    }

    // l reduction: sum over quads (keys were split across quad+regs)
#pragma unroll
    for (int s = 0; s < 2; s++) {
        l_r[s] += __shfl_xor(l_r[s], 16);
        l_r[s] += __shfl_xor(l_r[s], 32);
    }

    int b = bh >> 4, h = bh & 15;
#pragma unroll
    for (int s = 0; s < 2; s++)
#pragma unroll
        for (int r = 0; r < 4; r++) {
            float inv = 1.0f / __shfl(l_r[s], quad * 4 + r);   // lane q4r holds qrow q4r's sum
            int srow = qt * 128 + wid * 32 + s * 16 + quad * 4 + r;
#pragma unroll
            for (int t = 0; t < 4; t++)
                O[((long)(b * S_ + srow)) * 1024 + h * DH_ + t * 16 + l15] = f2bf(oacc[s][t][r] * inv);
        }
}

// ---------------- launch ----------------

extern "C" void kernel_launch(void* const* d_in, const int* in_sizes, int n_in,
                              void* d_out, int out_size, void* d_ws, size_t ws_size,
                              hipStream_t stream)
{
    const float* x  = (const float*)d_in[0];
    const float* Wq = (const float*)d_in[1];
    const float* Wk = (const float*)d_in[2];
    const float* Wv = (const float*)d_in[3];
    const float* Wo = (const float*)d_in[4];
    const float* fw = (const float*)d_in[5];
    float* out = (float*)d_out;

    char* ws = (char*)d_ws;
    unsigned short* xb    = (unsigned short*)(ws);               // 8 MB   [B*S, D] bf16
    unsigned short* WqkvT = (unsigned short*)(ws + 8388608);     // 6 MB   [3072,1024] bf16
    unsigned short* WoT   = (unsigned short*)(ws + 14680064);    // 2 MB   [1024,1024] bf16
    unsigned short* Qb    = (unsigned short*)(ws + 16777216);    // 8 MB   [B,H,S,64] bf16
    unsigned short* Kb    = (unsigned short*)(ws + 25165824);    // 8 MB   [B,H,S,64] bf16
    unsigned short* Vt    = (unsigned short*)(ws + 33554432);    // 8 MB   [B,H,64,S] fp16
    unsigned short* Ob    = xb;                                  // alias: xb dead after gemm1

    convert_x<<<dim3((B_ * S_ * D_) / 4 / 256), dim3(256), 0, stream>>>(x, xb, B_ * S_ * D_);
    transpose_w<<<dim3(32, 32, 4), dim3(32, 8), 0, stream>>>(
        Wq, Wk, Wv, Wo,
        WqkvT, WqkvT + 1024 * 1024, WqkvT + 2 * 1024 * 1024, WoT);
    gemm128<0><<<dim3(24, 32), dim3(256), 0, stream>>>(xb, WqkvT, Qb, Kb, Vt, (float*)nullptr);
    attn_kernel<<<dim3(S_ / 128, B_ * H_), dim3(256), 0, stream>>>(Qb, Kb, Vt, fw, Ob);
    gemm128<1><<<dim3(8, 32), dim3(256), 0, stream>>>(Ob, WoT,
        (unsigned short*)nullptr, (unsigned short*)nullptr, (unsigned short*)nullptr, out);
}

// Round 7
// 208.196 us; speedup vs baseline: 1.8368x; 1.0516x over previous
//
#include <hip/hip_runtime.h>
#include <hip/hip_bf16.h>
#include <stdint.h>

#define B_  2
#define S_  2048
#define D_  1024
#define H_  16
#define DH_ 64

typedef __attribute__((ext_vector_type(8))) __bf16    bf16x8;
typedef __attribute__((ext_vector_type(8))) _Float16  f16x8;
typedef __attribute__((ext_vector_type(2))) __fp16    fp16x2;   // cvt_pkrtz return type
typedef __attribute__((ext_vector_type(4))) float     f32x4;

__device__ inline unsigned short f2bf(float f) {
    union { float f; uint32_t u; } v; v.f = f;
    uint32_t r = (v.u + 0x7fffu + ((v.u >> 16) & 1u)) >> 16;
    return (unsigned short)r;
}

// async global->LDS, 16B per lane. LDS dest = wave-uniform base + lane*16.
__device__ __forceinline__ void g2l16(const unsigned short* g, unsigned short* l) {
    __builtin_amdgcn_global_load_lds(
        (const __attribute__((address_space(1))) unsigned int*)g,
        (__attribute__((address_space(3))) unsigned int*)l,
        16, 0, 0);
}

// ---------------- conversion kernels ----------------

__global__ void convert_x(const float* __restrict__ x, unsigned short* __restrict__ xb, int n) {
    int i = (blockIdx.x * blockDim.x + threadIdx.x) * 4;
    if (i < n) {
        float4 v = *(const float4*)(x + i);
        ushort4 o;
        o.x = f2bf(v.x); o.y = f2bf(v.y); o.z = f2bf(v.z); o.w = f2bf(v.w);
        *(ushort4*)(xb + i) = o;
    }
}

// transpose+convert 1024x1024 fp32 [K][N] -> bf16 [N][K]; z selects matrix
__global__ void transpose_w(const float* __restrict__ s0, const float* __restrict__ s1,
                            const float* __restrict__ s2, const float* __restrict__ s3,
                            unsigned short* __restrict__ d0, unsigned short* __restrict__ d1,
                            unsigned short* __restrict__ d2, unsigned short* __restrict__ d3) {
    __shared__ float tile[32][33];
    const float* src; unsigned short* dst;
    switch (blockIdx.z) {
        case 0: src = s0; dst = d0; break;
        case 1: src = s1; dst = d1; break;
        case 2: src = s2; dst = d2; break;
        default: src = s3; dst = d3; break;
    }
    int n0 = blockIdx.x * 32, k0 = blockIdx.y * 32;
    int tx = threadIdx.x, ty = threadIdx.y;   // (32, 8)
    for (int j = 0; j < 32; j += 8)
        tile[ty + j][tx] = src[(long)(k0 + ty + j) * 1024 + n0 + tx];
    __syncthreads();
    for (int j = 0; j < 32; j += 8)
        dst[(long)(n0 + ty + j) * 1024 + k0 + tx] = f2bf(tile[tx][ty + j]);
}

// ---------------- 128x128 MFMA GEMM, global_load_lds staging ----------------
// MODE 0: scatter epilogue -> Q[B,H,S,64] bf16 (PRE-SCALED by 0.125*log2e),
//         K[B,H,S,64] bf16, Vt[B,H,64,S] FP16
// MODE 1: C fp32 [M,1024] row-major
template<int MODE>
__global__ __launch_bounds__(256, 2)
void gemm128(const unsigned short* __restrict__ A, const unsigned short* __restrict__ Bt,
             unsigned short* __restrict__ Qo, unsigned short* __restrict__ Ko,
             unsigned short* __restrict__ Vt, float* __restrict__ Cout)
{
    __shared__ __align__(16) unsigned short As[128 * 64];
    __shared__ __align__(16) unsigned short Bs[128 * 64];
    const int tid  = threadIdx.x;
    const int lane = tid & 63, wid = tid >> 6;
    const int quad = lane >> 4, l15 = lane & 15;
    const int wm = wid >> 1, wn = wid & 1;
    const int bm = blockIdx.y, bn = blockIdx.x;
    const int K = 1024;
    f32x4 acc[4][4] = {};
    const long Abase = (long)bm * 128 * K;
    const long Bbase = (long)bn * 128 * K;

    for (int k0 = 0; k0 < K; k0 += 64) {
        __syncthreads();
#pragma unroll
        for (int i = 0; i < 4; i++) {
            int slot = i * 256 + wid * 64 + lane;
            int row = slot >> 3, cp = slot & 7;
            int c = cp ^ (row & 7);
            g2l16(A + Abase + (long)row * K + k0 + c * 8, &As[(i * 256 + wid * 64) * 8]);
        }
#pragma unroll
        for (int i = 0; i < 4; i++) {
            int slot = i * 256 + wid * 64 + lane;
            int row = slot >> 3, cp = slot & 7;
            int c = cp ^ (row & 7);
            g2l16(Bt + Bbase + (long)row * K + k0 + c * 8, &Bs[(i * 256 + wid * 64) * 8]);
        }
        __syncthreads();
#pragma unroll
        for (int ks = 0; ks < 2; ks++) {
            bf16x8 af[4], bfr[4];
#pragma unroll
            for (int t = 0; t < 4; t++) {
                int ra = wm * 64 + t * 16 + l15;
                af[t]  = *(const bf16x8*)(As + ra * 64 + (((ks * 4 + quad) ^ (l15 & 7))) * 8);
                int rb = wn * 64 + t * 16 + l15;
                bfr[t] = *(const bf16x8*)(Bs + rb * 64 + (((ks * 4 + quad) ^ (l15 & 7))) * 8);
            }
#pragma unroll
            for (int tm = 0; tm < 4; tm++)
#pragma unroll
                for (int tn = 0; tn < 4; tn++)
                    acc[tm][tn] = __builtin_amdgcn_mfma_f32_16x16x32_bf16(af[tm], bfr[tn], acc[tm][tn], 0, 0, 0);
        }
    }

    const float Cq = 0.125f * 1.44269504f;   // score scale * log2(e), folded into Q
    for (int tm = 0; tm < 4; tm++)
        for (int tn = 0; tn < 4; tn++)
            for (int r = 0; r < 4; r++) {
                int gm = bm * 128 + wm * 64 + tm * 16 + quad * 4 + r;
                int gn = bn * 128 + wn * 64 + tn * 16 + l15;
                float v = acc[tm][tn][r];
                if (MODE == 0) {
                    int b = gm >> 11, s = gm & 2047;
                    if (gn < 1024) {
                        int h = gn >> 6, d = gn & 63;
                        Qo[(((long)(b * H_ + h) * S_ + s) << 6) + d] = f2bf(v * Cq);
                    } else if (gn < 2048) {
                        int g = gn - 1024; int h = g >> 6, d = g & 63;
                        Ko[(((long)(b * H_ + h) * S_ + s) << 6) + d] = f2bf(v);
                    } else {
                        int g = gn - 2048; int h = g >> 6, d = g & 63;
                        union { _Float16 h; unsigned short u; } cv;
                        cv.h = (_Float16)v;                       // V^T stored FP16
                        Vt[((long)(b * H_ + h) * DH_ + d) * S_ + s] = cv.u;
                    }
                } else {
                    Cout[(long)gm * 1024 + gn] = v;
                }
            }
}

// ---------------- flash attention: S^T trick + fp16 P/V ----------------
// grid (S/128, B*H), 256 threads = 4 waves, 32 q-rows/wave.
// S^T = mfma(K_frag, Q_frag): accumulator comes out transposed (row=key=
// quad*4+r, col=qrow=l15); each lane's 4 acc regs are 4 CONSECUTIVE KEYS,
// so P packs via v_cvt_pkrtz and writes as b64 stores. PV runs fp16 mfma
// with V^T staged fp16. Q is pre-scaled by 0.125*log2e at the gemm epilogue
// and fw is loaded RAW -> softmax block is: 1 v_mul + 1 v_exp per element
// (__builtin_amdgcn_exp2f = bare v_exp_f32; OCML exp2f edge-handling was
// suspect #1 for the 50% VALUBusy).
// Softmax max-free: fractal weights sum to 1 => |w*s| < ~0.1.
__global__ __launch_bounds__(256, 3)
void attn_kernel(const unsigned short* __restrict__ Q, const unsigned short* __restrict__ Kb,
                 const unsigned short* __restrict__ Vt, const float* __restrict__ fw,
                 unsigned short* __restrict__ O)
{
    __shared__ __align__(16) unsigned short Ks[2][64 * 64];
    __shared__ __align__(16) unsigned short Vs[2][64 * 64];
    __shared__ __align__(16) unsigned short P[4][32 * 72];   // fp16 bits, row=qrow, col=key

    const int tid  = threadIdx.x;
    const int lane = tid & 63, wid = tid >> 6;
    const int quad = lane >> 4, l15 = lane & 15;
    const int bh = blockIdx.y;
    const int qt = blockIdx.x;

    const unsigned short* Kg = Kb + (long)bh * S_ * DH_;
    const unsigned short* Vg = Vt + (long)bh * (long)DH_ * S_;

    bf16x8 qf[2][2];
#pragma unroll
    for (int s = 0; s < 2; s++) {
        const unsigned short* Qp = Q + ((long)bh * S_ + qt * 128 + wid * 32 + s * 16 + l15) * DH_ + quad * 8;
        qf[s][0] = *(const bf16x8*)(Qp);
        qf[s][1] = *(const bf16x8*)(Qp + 32);
    }

    auto issue = [&](int buf, int kt) {
#pragma unroll
        for (int i = 0; i < 2; i++) {
            int slot = wid * 128 + i * 64 + lane;
            int row = slot >> 3, cp = slot & 7;
            int c = cp ^ (row & 7);
            g2l16(Kg + ((long)(kt * 64 + row) * 64 + c * 8), &Ks[buf][(wid * 128 + i * 64) * 8]);
        }
#pragma unroll
        for (int i = 0; i < 2; i++) {
            int slot = wid * 128 + i * 64 + lane;
            int row = slot >> 3, cp = slot & 7;
            int c = cp ^ (row & 7);
            g2l16(Vg + ((long)row * S_ + kt * 64 + c * 8), &Vs[buf][(wid * 128 + i * 64) * 8]);
        }
    };

    f32x4 oacc[2][4] = {};
    float l_r[2] = {0.f, 0.f};

    issue(0, 0);
    __syncthreads();

    for (int kt = 0; kt < S_ / 64; kt++) {
        const int cur = kt & 1;
        if (kt + 1 < S_ / 64) issue(1 - cur, kt + 1);

        // raw per-key fractal weights (score scale pre-folded into Q)
        f32x4 wvc[4];
#pragma unroll
        for (int t = 0; t < 4; t++) {
            float4 w = *(const float4*)(fw + kt * 64 + t * 16 + quad * 4);
            wvc[t][0] = w.x; wvc[t][1] = w.y; wvc[t][2] = w.z; wvc[t][3] = w.w;
        }

        const unsigned short* Kc = &Ks[cur][0];
        const unsigned short* Vc = &Vs[cur][0];

        // ---- S^T tiles: mfma(K_frag, Q_frag) -> row=key(quad*4+r), col=qrow(l15) ----
        f32x4 sacc[2][4] = {};
#pragma unroll
        for (int t = 0; t < 4; t++) {
            int row = t * 16 + l15;
            bf16x8 k0 = *(const bf16x8*)(Kc + (row * 8 + (quad       ^ (l15 & 7))) * 8);
            bf16x8 k1 = *(const bf16x8*)(Kc + (row * 8 + ((4 + quad) ^ (l15 & 7))) * 8);
#pragma unroll
            for (int s = 0; s < 2; s++) {
                sacc[s][t] = __builtin_amdgcn_mfma_f32_16x16x32_bf16(k0, qf[s][0], sacc[s][t], 0, 0, 0);
                sacc[s][t] = __builtin_amdgcn_mfma_f32_16x16x32_bf16(k1, qf[s][1], sacc[s][t], 0, 0, 0);
            }
        }

        // ---- p = 2^(s*w); packed fp16 P write (b64) ----
        unsigned short* pb = &P[wid][0];
#pragma unroll
        for (int s = 0; s < 2; s++) {
#pragma unroll
            for (int t = 0; t < 4; t++) {
                float p0 = __builtin_amdgcn_exp2f(sacc[s][t][0] * wvc[t][0]);
                float p1 = __builtin_amdgcn_exp2f(sacc[s][t][1] * wvc[t][1]);
                float p2 = __builtin_amdgcn_exp2f(sacc[s][t][2] * wvc[t][2]);
                float p3 = __builtin_amdgcn_exp2f(sacc[s][t][3] * wvc[t][3]);
                l_r[s] += (p0 + p1) + (p2 + p3);
                union { fp16x2 h; unsigned int u; } a, b;
                a.h = __builtin_amdgcn_cvt_pkrtz(p0, p1);
                b.h = __builtin_amdgcn_cvt_pkrtz(p2, p3);
                *(uint2*)(pb + (s * 16 + l15) * 72 + t * 16 + quad * 4) = make_uint2(a.u, b.u);
            }
        }

        // ---- O += P V (fp16 mfma); both strips share each V fragment read ----
#pragma unroll
        for (int ks = 0; ks < 2; ks++) {
            f16x8 pf0 = *(const f16x8*)(pb + l15 * 72 + ks * 32 + quad * 8);
            f16x8 pf1 = *(const f16x8*)(pb + (16 + l15) * 72 + ks * 32 + quad * 8);
#pragma unroll
            for (int t = 0; t < 4; t++) {
                int row = t * 16 + l15;
                f16x8 vf = *(const f16x8*)(Vc + (row * 8 + ((ks * 4 + quad) ^ (l15 & 7))) * 8);
                oacc[0][t] = __builtin_amdgcn_mfma_f32_16x16x32_f16(pf0, vf, oacc[0][t], 0, 0, 0);
                oacc[1][t] = __builtin_amdgcn_mfma_f32_16x16x32_f16(pf1, vf, oacc[1][t], 0, 0, 0);
            }
        }

        __syncthreads();
    }

    // l reduction: sum over quads (keys were split across quad+regs)
#pragma unroll
    for (int s = 0; s < 2; s++) {
        l_r[s] += __shfl_xor(l_r[s], 16);
        l_r[s] += __shfl_xor(l_r[s], 32);
    }

    int b = bh >> 4, h = bh & 15;
#pragma unroll
    for (int s = 0; s < 2; s++)
#pragma unroll
        for (int r = 0; r < 4; r++) {
            float inv = 1.0f / __shfl(l_r[s], quad * 4 + r);   // lane q4r holds qrow q4r's sum
            int srow = qt * 128 + wid * 32 + s * 16 + quad * 4 + r;
#pragma unroll
            for (int t = 0; t < 4; t++)
                O[((long)(b * S_ + srow)) * 1024 + h * DH_ + t * 16 + l15] = f2bf(oacc[s][t][r] * inv);
        }
}

// ---------------- launch ----------------

extern "C" void kernel_launch(void* const* d_in, const int* in_sizes, int n_in,
                              void* d_out, int out_size, void* d_ws, size_t ws_size,
                              hipStream_t stream)
{
    const float* x  = (const float*)d_in[0];
    const float* Wq = (const float*)d_in[1];
    const float* Wk = (const float*)d_in[2];
    const float* Wv = (const float*)d_in[3];
    const float* Wo = (const float*)d_in[4];
    const float* fw = (const float*)d_in[5];
    float* out = (float*)d_out;

    char* ws = (char*)d_ws;
    unsigned short* xb    = (unsigned short*)(ws);               // 8 MB   [B*S, D] bf16
    unsigned short* WqkvT = (unsigned short*)(ws + 8388608);     // 6 MB   [3072,1024] bf16
    unsigned short* WoT   = (unsigned short*)(ws + 14680064);    // 2 MB   [1024,1024] bf16
    unsigned short* Qb    = (unsigned short*)(ws + 16777216);    // 8 MB   [B,H,S,64] bf16 (pre-scaled)
    unsigned short* Kb    = (unsigned short*)(ws + 25165824);    // 8 MB   [B,H,S,64] bf16
    unsigned short* Vt    = (unsigned short*)(ws + 33554432);    // 8 MB   [B,H,64,S] fp16
    unsigned short* Ob    = xb;                                  // alias: xb dead after gemm1

    convert_x<<<dim3((B_ * S_ * D_) / 4 / 256), dim3(256), 0, stream>>>(x, xb, B_ * S_ * D_);
    transpose_w<<<dim3(32, 32, 4), dim3(32, 8), 0, stream>>>(
        Wq, Wk, Wv, Wo,
        WqkvT, WqkvT + 1024 * 1024, WqkvT + 2 * 1024 * 1024, WoT);
    gemm128<0><<<dim3(24, 32), dim3(256), 0, stream>>>(xb, WqkvT, Qb, Kb, Vt, (float*)nullptr);
    attn_kernel<<<dim3(S_ / 128, B_ * H_), dim3(256), 0, stream>>>(Qb, Kb, Vt, fw, Ob);
    gemm128<1><<<dim3(8, 32), dim3(256), 0, stream>>>(Ob, WoT,
        (unsigned short*)nullptr, (unsigned short*)nullptr, (unsigned short*)nullptr, out);
}